// Round 4
// baseline (192.329 us; speedup 1.0000x reference)
//
#include <hip/hip_runtime.h>
#include <hip/hip_bf16.h>
#include <math.h>

// Loss_26886495273741: uniformity loss
//   dots = F F^T (diag masked), I = argmax_row(dots), d = ||F - F[I] + eps||_2
//   loss = -mean(log(n*d))
// F: [16384, 256] fp32.
//
// Round 4: A-persist-in-registers MFMA kernel.
//   Grid = 128 row-stripes x 8 col-chunks (chunk = blockIdx&7 -> XCD affinity).
//   A panel [128][256] bf16 staged to LDS once, extracted to 128 VGPRs/lane
//   (af[4][8]), then A-LDS region is reused for the B double buffer (BK=64,
//   2 x 16 KB). One barrier per K=64 step (32 MFMA between barriers),
//   prefetch-1 covers L2 latency. 8-way XOR swizzle on B rows.
//   Argmax fold: biased-float monotonic u32 keys (quant 2^-3 in dot space),
//   u32 max tree per tile; u64 atomicMax once per block per row.

#define NROWS 16384
#define DIM   256
#define BM    128
#define BN    128
#define CCOLS 2048
#define TILES (CCOLS / BN)     // 16
#define STEPS (TILES * 4)      // 64 K=64 steps
#define EPSF  1e-6f

typedef __attribute__((ext_vector_type(8))) __bf16 bf16x8;
typedef __attribute__((ext_vector_type(4))) float f32x4;

typedef const __attribute__((address_space(1))) void* gas1_t;
typedef __attribute__((address_space(3))) void* las3_t;

__device__ __forceinline__ void glds16(const void* g, void* l) {
    __builtin_amdgcn_global_load_lds((gas1_t)g, (las3_t)l, 16, 0, 0);
}

__device__ __forceinline__ unsigned short f2bf(float f) {
    union { float f; unsigned u; } x; x.f = f;
    const unsigned u = x.u;
    return (unsigned short)((u + 0x7FFFu + ((u >> 16) & 1u)) >> 16);  // RNE
}

__device__ __forceinline__ unsigned umax2(unsigned a, unsigned b) {
    return a > b ? a : b;
}

// ---------------- K0: convert fp32 -> bf16, zero packed ----------------
__global__ __launch_bounds__(256)
void convert_kernel(const float* __restrict__ F, unsigned short* __restrict__ Fb,
                    unsigned long long* __restrict__ packed)
{
    const int t = blockIdx.x * 256 + threadIdx.x;     // 524288 threads
    const float4 a = *reinterpret_cast<const float4*>(F + (size_t)t * 8);
    const float4 b = *reinterpret_cast<const float4*>(F + (size_t)t * 8 + 4);
    ushort4 lo, hi;
    lo.x = f2bf(a.x); lo.y = f2bf(a.y); lo.z = f2bf(a.z); lo.w = f2bf(a.w);
    hi.x = f2bf(b.x); hi.y = f2bf(b.y); hi.z = f2bf(b.z); hi.w = f2bf(b.w);
    *reinterpret_cast<ushort4*>(Fb + (size_t)t * 8)     = lo;
    *reinterpret_cast<ushort4*>(Fb + (size_t)t * 8 + 4) = hi;
    if (t < NROWS) packed[t] = 0ull;
}

// ---------------- K1: A-persist bf16 MFMA + per-row argmax ----------------
__global__ __launch_bounds__(256, 2)
void mfma_apersist_kernel(const unsigned short* __restrict__ Fb,
                          unsigned long long* __restrict__ packed)
{
    __shared__ __align__(16) unsigned short As[BM * DIM];   // 64 KB
    unsigned short* const Bs = As;   // B dbuf (2 x 8192 shorts) overlays dead A

    const int tid   = threadIdx.x;
    const int w     = tid >> 6;
    const int l     = tid & 63;
    const int chunk = (int)blockIdx.x & 7;          // -> XCD affinity
    const int rs    = (int)blockIdx.x >> 3;
    const int row0  = rs * BM;
    const int ccol0 = chunk * CCOLS;
    const int dtile = (chunk == (rs >> 4)) ? (rs & 15) : -1;

    const int wrow = (w >> 1) * 64;
    const int wcol = (w & 1) * 64;
    const int lc   = l & 15;
    const int lr4  = l >> 4;

    // ---- stage A panel: LDS phys (row, cp) holds global chunk cp^(row&7) ----
    {
        const int lr = l >> 5;                       // 0..1
        const int sc = (l & 31) ^ (2 * w + lr);      // pre-permuted source chunk
        #pragma unroll
        for (int t = 0; t < 16; ++t) {
            const int r = 8 * t + 2 * w + lr;
            glds16(Fb + (size_t)(row0 + r) * DIM + sc * 8,
                   &As[(t * 4 + w) * 512]);
        }
    }
    __syncthreads();

    // ---- extract A fragments to registers: af[i][kt], kt = K/32 step ----
    bf16x8 af[4][8];
    #pragma unroll
    for (int i = 0; i < 4; ++i) {
        const int r = wrow + i * 16 + lc;
        #pragma unroll
        for (int kt = 0; kt < 8; ++kt) {
            const int g = kt * 4 + lr4;
            af[i][kt] = *reinterpret_cast<const bf16x8*>(
                &As[r * 256 + ((g ^ (r & 7)) << 3)]);
        }
    }
    __syncthreads();   // A region now reusable for B staging

    // ---- B staging geometry (slice = 128 cols x 64 shorts, 8-way swizzle) ----
    // issue covers 8 cols; lane l: col = base + (l>>3), phys chunk p = l&7
    // stored global chunk = p ^ (col&7) -> source chunk = (l&7)^((l>>3)&7)
    const int bsc = (l & 7) ^ ((l >> 3) & 7);
    const int bco = l >> 3;

    // stage slice 0 into buf 0
    #pragma unroll
    for (int t = 0; t < 4; ++t) {
        const int grp = t * 4 + w;
        glds16(Fb + (size_t)(ccol0 + grp * 8 + bco) * DIM + bsc * 8,
               &Bs[grp * 512]);
    }

    f32x4 acc[4][4] = {};
    unsigned best[4][4] = {};   // packed (quantized biased-float | 2047-local_c)

    for (int tile = 0; tile < TILES; ++tile) {
        #pragma unroll
        for (int kq = 0; kq < 4; ++kq) {
            __syncthreads();   // slice s=tile*4+kq staged (vmcnt drained)

            // prefetch slice s+1 into buf (kq&1)^1
            if (tile * 4 + kq + 1 < STEPS) {
                const int ns   = tile * 4 + kq + 1;
                const int nc0  = ccol0 + (ns >> 2) * BN;
                const int nk0  = (ns & 3) * 64;
                const int nbuf = (kq & 1) ^ 1;
                #pragma unroll
                for (int t = 0; t < 4; ++t) {
                    const int grp = t * 4 + w;
                    glds16(Fb + (size_t)(nc0 + grp * 8 + bco) * DIM + nk0 + bsc * 8,
                           &Bs[nbuf * 8192 + grp * 512]);
                }
            }

            const int rbase = (kq & 1) * 8192;
            #pragma unroll
            for (int h = 0; h < 2; ++h) {           // two K=32 halves
                bf16x8 bfv[4];
                #pragma unroll
                for (int j = 0; j < 4; ++j) {
                    const int c = wcol + j * 16 + lc;
                    const int p = (h * 4 + lr4) ^ (c & 7);
                    bfv[j] = *reinterpret_cast<const bf16x8*>(
                        &Bs[rbase + c * 64 + p * 8]);
                }
                #pragma unroll
                for (int j = 0; j < 4; ++j)
                    #pragma unroll
                    for (int i = 0; i < 4; ++i)
                        acc[i][j] = __builtin_amdgcn_mfma_f32_16x16x32_bf16(
                            af[i][kq * 2 + h], bfv[j], acc[i][j], 0, 0, 0);
            }
        }

        // ---- fold tile into running argmax (u32 keys) ----
        unsigned cb[4];
        #pragma unroll
        for (int j = 0; j < 4; ++j)
            cb[j] = 2047u - (unsigned)(tile * 128 + wcol + j * 16 + lc);

        if (tile == dtile) {       // diagonal tile: mask c==r
            #pragma unroll
            for (int i = 0; i < 4; ++i)
                #pragma unroll
                for (int g = 0; g < 4; ++g) {
                    const int r_loc = wrow + i * 16 + lr4 * 4 + g;
                    unsigned bk = best[i][g];
                    #pragma unroll
                    for (int j = 0; j < 4; ++j) {
                        const int c_loc = wcol + j * 16 + lc;
                        unsigned k = (__float_as_uint(acc[i][j][g] + 512.f)
                                      & 0xFFFFF800u) | cb[j];
                        if (c_loc == r_loc) k = 0u;
                        bk = umax2(bk, k);
                        acc[i][j][g] = 0.f;
                    }
                    best[i][g] = bk;
                }
        } else {
            #pragma unroll
            for (int i = 0; i < 4; ++i)
                #pragma unroll
                for (int g = 0; g < 4; ++g) {
                    const unsigned k0 = (__float_as_uint(acc[i][0][g] + 512.f)
                                         & 0xFFFFF800u) | cb[0];
                    const unsigned k1 = (__float_as_uint(acc[i][1][g] + 512.f)
                                         & 0xFFFFF800u) | cb[1];
                    const unsigned k2 = (__float_as_uint(acc[i][2][g] + 512.f)
                                         & 0xFFFFF800u) | cb[2];
                    const unsigned k3 = (__float_as_uint(acc[i][3][g] + 512.f)
                                         & 0xFFFFF800u) | cb[3];
                    best[i][g] = umax2(best[i][g],
                                       umax2(umax2(k0, k1), umax2(k2, k3)));
                    acc[i][0][g] = 0.f; acc[i][1][g] = 0.f;
                    acc[i][2][g] = 0.f; acc[i][3][g] = 0.f;
                }
        }
    }

    // ---- once per block: reduce over 16-lane col group, one u64 atomic ----
    #pragma unroll
    for (int i = 0; i < 4; ++i)
        #pragma unroll
        for (int g = 0; g < 4; ++g) {
            unsigned k = best[i][g];
            #pragma unroll
            for (int m = 8; m >= 1; m >>= 1)
                k = umax2(k, (unsigned)__shfl_xor((int)k, m));
            if (lc == 0) {
                const int r = row0 + wrow + i * 16 + lr4 * 4 + g;
                const unsigned c = (unsigned)ccol0 + (2047u - (k & 0x7FFu));
                const unsigned long long pk =
                    ((unsigned long long)(k & 0xFFFFF800u) << 32) |
                    (0xFFFFFFFFu - c);
                atomicMax(&packed[r], pk);
            }
        }
}

// ---------------- K2: exact fp32 distances + log terms ----------------
__global__ __launch_bounds__(256)
void dist_loss_kernel(const float* __restrict__ F,
                      const unsigned long long* __restrict__ packed,
                      double* __restrict__ partials)
{
    const int tid  = threadIdx.x;
    const int lane = tid & 63;
    const int w    = tid >> 6;
    const int gw   = blockIdx.x * 4 + w;       // 1024 waves
    double local = 0.0;
    for (int r = gw; r < NROWS; r += 1024) {
        const unsigned long long p = packed[r];
        const int idx = (int)(0xFFFFFFFFu - (unsigned)(p & 0xFFFFFFFFull));
        const float4 a = *reinterpret_cast<const float4*>(
            F + (size_t)r * DIM + (lane << 2));
        const float4 b = *reinterpret_cast<const float4*>(
            F + (size_t)idx * DIM + (lane << 2));
        const float dx = a.x - b.x + EPSF;
        const float dy = a.y - b.y + EPSF;
        const float dz = a.z - b.z + EPSF;
        const float dw = a.w - b.w + EPSF;
        float ss = dx * dx + dy * dy + dz * dz + dw * dw;
        #pragma unroll
        for (int m = 32; m >= 1; m >>= 1) ss += __shfl_xor(ss, m);
        if (lane == 0)
            local += 0.5 * log((double)ss) + log((double)NROWS);
    }
    __shared__ double sm[4];
    if (lane == 0) sm[w] = local;
    __syncthreads();
    if (tid == 0) partials[blockIdx.x] = sm[0] + sm[1] + sm[2] + sm[3];
}

__global__ __launch_bounds__(256)
void finalize_kernel(const double* __restrict__ partials, float* __restrict__ out)
{
    const int tid = threadIdx.x;
    double v = partials[tid];
    #pragma unroll
    for (int m = 32; m >= 1; m >>= 1) v += __shfl_xor(v, m);
    __shared__ double sm[4];
    if ((tid & 63) == 0) sm[tid >> 6] = v;
    __syncthreads();
    if (tid == 0) out[0] = (float)(-(sm[0] + sm[1] + sm[2] + sm[3]) / (double)NROWS);
}

extern "C" void kernel_launch(void* const* d_in, const int* in_sizes, int n_in,
                              void* d_out, int out_size, void* d_ws, size_t ws_size,
                              hipStream_t stream)
{
    const float* F   = (const float*)d_in[0];
    float*       out = (float*)d_out;

    unsigned short*     Fb       = (unsigned short*)d_ws;                       // 8 MB
    unsigned long long* packed   = (unsigned long long*)((char*)d_ws + (size_t)NROWS * DIM * 2);
    double*             partials = (double*)((char*)packed + (size_t)NROWS * 8);

    convert_kernel<<<2048, 256, 0, stream>>>(F, Fb, packed);
    mfma_apersist_kernel<<<(NROWS / BM) * 8, 256, 0, stream>>>(Fb, packed);
    dist_loss_kernel<<<256, 256, 0, stream>>>(F, packed, partials);
    finalize_kernel<<<1, 256, 0, stream>>>(partials, out);
}